// Round 8
// baseline (85.956 us; speedup 1.0000x reference)
//
#include <hip/hip_runtime.h>
#include <hip/hip_bf16.h>
#include <float.h>

// Problem constants (fixed by setup_inputs)
constexpr int B = 8, N = 4096, M = 4096, E = 12288;
constexpr int TB = 512;                       // threads per block
constexpr int EDGE_BLOCKS = (B * E) / TB;     // 192 (first in grid)
constexpr int QB = 128;                       // queries per chamfer block
constexpr int CHAM_BLOCKS = 2 * B * (N / QB); // 512
constexpr int SPLIT = 32;                     // ref-sweep split across thread groups
constexpr int RPT = M / SPLIT;                // 128 refs per thread
constexpr int VEC = 8;                        // register queries per thread
constexpr int NPTS = 2 * B * N;               // 65536 packed points

// ws layout:
//   float4 pts4[NPTS]            @ float4-offset 0   (pred b-major, then gt)
//   float  edge_part[2*192]      @ float-offset 4*NPTS
//   float  cham_part[512]        @ float-offset 4*NPTS + 384
// Every slot written unconditionally -> 0xAA poison harmless, no init kernel.

__global__ __launch_bounds__(256) void pack_kernel(
    const float* __restrict__ pred, const float* __restrict__ gt,
    float4* __restrict__ pts4) {
    const int i = blockIdx.x * 256 + threadIdx.x;      // 0..65535
    const float* src = (i < B * N) ? pred : gt;
    const float* p = src + (size_t)(i & (B * N - 1)) * 3;
    const float x = p[0], y = p[1], z = p[2];
    pts4[i] = make_float4(x, y, z, 0.5f * (x * x + y * y + z * z));
}

__global__ __launch_bounds__(TB) void fused_kernel(
    const float* __restrict__ pred, const int* __restrict__ edges,
    const float4* __restrict__ pts4, float* __restrict__ wsf) {
    const int bid = blockIdx.x;
    const int t = threadIdx.x;

    __shared__ float red[SPLIT * QB];          // 16 KB
    __shared__ float wsum[8], wsum2[8];

    if (bid >= EDGE_BLOCKS) {
        // ---------------- chamfer block (no ref LDS, reads L2) ----------------
        const int cb  = bid - EDGE_BLOCKS;     // 0..511
        const int dir = cb >> 8;               // 0: q=pred/ref=gt, 1: swapped
        const int b   = (cb >> 5) & 7;
        const int qt  = cb & 31;               // 32 query tiles of 128
        const float4* __restrict__ q4 = pts4 + (dir ? B * N : 0) + b * N;
        const float4* __restrict__ r4 = pts4 + (dir ? 0 : B * N) + b * M;

        const int ql = t & 15;                 // 0..15
        const int s  = t >> 4;                 // 0..31 -> ref segment

        // this thread's VEC=8 register queries (w added back in tail)
        float qx[VEC], qy[VEC], qz[VEC];
#pragma unroll
        for (int i = 0; i < VEC; i++) {
            const float4 Q = q4[qt * QB + ql + i * 16];
            qx[i] = Q.x; qy[i] = Q.y; qz[i] = Q.z;
        }

        const float4* __restrict__ tb = r4 + s * RPT;
        float mn[VEC];
#pragma unroll
        for (int i = 0; i < VEC; i++) mn[i] = FLT_MAX;

        // 4-point register prefetch straight from global (L2-resident)
        float4 pA = tb[0], pB = tb[1], pC = tb[2], pD = tb[3];
#pragma unroll 2
        for (int m = 0; m < RPT - 4; m += 4) {
            const float4 nA = tb[m + 4], nB = tb[m + 5];
            const float4 nC = tb[m + 6], nD = tb[m + 7];
#pragma unroll
            for (int i = 0; i < VEC; i++) {
                float d0 = fmaf(-qz[i], pA.z, pA.w);
                d0 = fmaf(-qy[i], pA.y, d0);
                d0 = fmaf(-qx[i], pA.x, d0);
                float d1 = fmaf(-qz[i], pB.z, pB.w);
                d1 = fmaf(-qy[i], pB.y, d1);
                d1 = fmaf(-qx[i], pB.x, d1);
                float d2 = fmaf(-qz[i], pC.z, pC.w);
                d2 = fmaf(-qy[i], pC.y, d2);
                d2 = fmaf(-qx[i], pC.x, d2);
                float d3 = fmaf(-qz[i], pD.z, pD.w);
                d3 = fmaf(-qy[i], pD.y, d3);
                d3 = fmaf(-qx[i], pD.x, d3);
                mn[i] = fminf(mn[i], fminf(d0, d1));   // -> v_min3_f32
                mn[i] = fminf(mn[i], fminf(d2, d3));
            }
            pA = nA; pB = nB; pC = nC; pD = nD;
        }
#pragma unroll
        for (int i = 0; i < VEC; i++) {
            float d0 = fmaf(-qz[i], pA.z, pA.w);
            d0 = fmaf(-qy[i], pA.y, d0);
            d0 = fmaf(-qx[i], pA.x, d0);
            float d1 = fmaf(-qz[i], pB.z, pB.w);
            d1 = fmaf(-qy[i], pB.y, d1);
            d1 = fmaf(-qx[i], pB.x, d1);
            float d2 = fmaf(-qz[i], pC.z, pC.w);
            d2 = fmaf(-qy[i], pC.y, d2);
            d2 = fmaf(-qx[i], pC.x, d2);
            float d3 = fmaf(-qz[i], pD.z, pD.w);
            d3 = fmaf(-qy[i], pD.y, d3);
            d3 = fmaf(-qx[i], pD.x, d3);
            mn[i] = fminf(mn[i], fminf(d0, d1));
            mn[i] = fminf(mn[i], fminf(d2, d3));
        }

        // seg-major partials red[s][q]
#pragma unroll
        for (int i = 0; i < VEC; i++)
            red[s * QB + ql + i * 16] = mn[i];
        __syncthreads();

        float sv = 0.0f;
        if (t < QB) {
            float m = red[t];                  // column reads: 2 lanes/bank, free
#pragma unroll 8
            for (int k = 1; k < SPLIT; k++) m = fminf(m, red[k * QB + t]);
            const float4 Q = q4[qt * QB + t];
            sv = sqrtf(fmaxf(2.0f * m + (Q.w + Q.w), 0.0f));  // + |q|^2
        }
#pragma unroll
        for (int o = 32; o > 0; o >>= 1) sv += __shfl_down(sv, o, 64);
        if ((t & 63) == 0) wsum[t >> 6] = sv;
        __syncthreads();
        if (t == 0)
            wsf[2 * EDGE_BLOCKS + cb] = wsum[0] + wsum[1];   // waves 2..7 were zero
    } else {
        // ---------------- edge-length block ----------------
        const int eg = bid * TB + t;           // 0..98303
        const int b  = eg / E;
        const int e  = eg - b * E;
        const int i0 = edges[2 * e], i1 = edges[2 * e + 1];
        const float* p0 = pred + ((size_t)b * N + i0) * 3;
        const float* p1 = pred + ((size_t)b * N + i1) * 3;
        const float dx = p0[0] - p1[0];
        const float dy = p0[1] - p1[1];
        const float dz = p0[2] - p1[2];
        float L  = sqrtf(dx * dx + dy * dy + dz * dz);
        float L2 = L * L;
#pragma unroll
        for (int o = 32; o > 0; o >>= 1) {
            L  += __shfl_down(L, o, 64);
            L2 += __shfl_down(L2, o, 64);
        }
        const int wv = t >> 6;
        if ((t & 63) == 0) { wsum[wv] = L; wsum2[wv] = L2; }
        __syncthreads();
        if (t == 0) {
            float a = 0.0f, c = 0.0f;
#pragma unroll
            for (int w = 0; w < 8; w++) { a += wsum[w]; c += wsum2[w]; }
            wsf[2 * bid]     = a;
            wsf[2 * bid + 1] = c;
        }
    }
}

__global__ __launch_bounds__(TB) void final_kernel(
    const float* __restrict__ wsf, float* __restrict__ out) {
    const int t = threadIdx.x;
    float sc = wsf[2 * EDGE_BLOCKS + t];       // 512 chamfer partials
    float s1 = 0.0f, s2 = 0.0f;
    if (t < EDGE_BLOCKS) {
        s1 = wsf[2 * t];
        s2 = wsf[2 * t + 1];
    }
#pragma unroll
    for (int o = 32; o > 0; o >>= 1) {
        sc += __shfl_down(sc, o, 64);
        s1 += __shfl_down(s1, o, 64);
        s2 += __shfl_down(s2, o, 64);
    }
    __shared__ float w[3][8];
    const int wv = t >> 6, ln = t & 63;
    if (ln == 0) { w[0][wv] = sc; w[1][wv] = s1; w[2][wv] = s2; }
    __syncthreads();
    if (t == 0) {
        float S = 0.0f, A = 0.0f, C = 0.0f;
#pragma unroll
        for (int i = 0; i < 8; i++) { S += w[0][i]; A += w[1][i]; C += w[2][i]; }
        const float K = (float)(B * E);        // 98304
        const float var = (C - A * A / K) / (K - 1.0f);
        out[0] = S / 32768.0f + 0.1f * var;    // cd + 0.1 * edge_var
    }
}

extern "C" void kernel_launch(void* const* d_in, const int* in_sizes, int n_in,
                              void* d_out, int out_size, void* d_ws, size_t ws_size,
                              hipStream_t stream) {
    const float* pred  = (const float*)d_in[0];
    const float* gt    = (const float*)d_in[1];
    const int*   edges = (const int*)d_in[2];
    float* out = (float*)d_out;
    float4* pts4 = (float4*)d_ws;
    float*  wsf  = (float*)d_ws + (size_t)4 * NPTS;

    pack_kernel<<<NPTS / 256, 256, 0, stream>>>(pred, gt, pts4);
    fused_kernel<<<EDGE_BLOCKS + CHAM_BLOCKS, TB, 0, stream>>>(pred, edges, pts4, wsf);
    final_kernel<<<1, TB, 0, stream>>>(wsf, out);
}